// Round 2
// baseline (701.006 us; speedup 1.0000x reference)
//
#include <hip/hip_runtime.h>

typedef __bf16 bf16_t;
typedef __bf16 v8bf __attribute__((ext_vector_type(8)));
typedef __bf16 v4bf __attribute__((ext_vector_type(4)));
typedef float  v4f  __attribute__((ext_vector_type(4)));

#define D_MODEL 1024
#define NHEAD   16
#define DHEAD   64
#define SEQ     2048
#define BATCH   4
#define ROWS    (BATCH*SEQ)   // 8192

// ---------------------------------------------------------------- converts
__global__ __launch_bounds__(256) void k_f32_to_bf16(const float* __restrict__ src,
                                                     bf16_t* __restrict__ dst, int n4) {
    int i = blockIdx.x * 256 + threadIdx.x;
    if (i >= n4) return;
    float4 f = ((const float4*)src)[i];
    v4bf o;
    o[0] = (bf16_t)f.x; o[1] = (bf16_t)f.y; o[2] = (bf16_t)f.z; o[3] = (bf16_t)f.w;
    ((v4bf*)dst)[i] = o;
}

__global__ __launch_bounds__(256) void k_pack_bias(const float* __restrict__ a,
                                                   const float* __restrict__ b,
                                                   const float* __restrict__ c,
                                                   float* __restrict__ dst) {
    int i = blockIdx.x * 256 + threadIdx.x;
    if (i < 1024) { dst[i] = a[i]; dst[i + 1024] = b[i]; dst[i + 2048] = c[i]; }
}

// ---------------------------------------------------------------- GEMM  C = A * B^T (+bias) (+resid)
// A: [M,K] bf16 row-major.  Bm: [N,K] bf16 row-major (i.e. torch Linear weight).
// If Cf != null: Cf[row,col] = acc + bias[col] + resid[row,col]  (fp32 out)
// else:          Cb[row,col] = bf16(acc + bias[col])
#define BK  32
#define LDT 40   // padded LDS row stride (elems); 40*2=80B -> 20-bank shift/row

__global__ __launch_bounds__(256, 2) void k_gemm_bt(
    const bf16_t* __restrict__ A, const bf16_t* __restrict__ Bm,
    const float* __restrict__ bias, const float* __restrict__ resid,
    bf16_t* __restrict__ Cb, float* __restrict__ Cf,
    int M, int N, int K)
{
    __shared__ bf16_t As[128 * LDT];
    __shared__ bf16_t Bs[128 * LDT];

    int nTile = N >> 7;
    int m0 = (blockIdx.x / nTile) << 7;
    int n0 = (blockIdx.x % nTile) << 7;
    int t = threadIdx.x;
    int w = t >> 6, lane = t & 63, quad = lane >> 4, ln = lane & 15;
    int wm = (w >> 1) << 6, wn = (w & 1) << 6;

    // staging: 512 16B-chunks per tile; thread does chunk t (rows 0..63) and t+256 (rows 64..127)
    int r0 = t >> 2;
    int c0 = (t & 3) << 3;
    const bf16_t* Ag = A + (size_t)(m0 + r0) * K + c0;
    const bf16_t* Bg = Bm + (size_t)(n0 + r0) * K + c0;

    v4f acc[4][4];
#pragma unroll
    for (int i = 0; i < 4; i++)
#pragma unroll
        for (int j = 0; j < 4; j++) acc[i][j] = (v4f){0.f, 0.f, 0.f, 0.f};

    for (int k0 = 0; k0 < K; k0 += BK) {
        uint4 a0 = *(const uint4*)(Ag + k0);
        uint4 a1 = *(const uint4*)(Ag + (size_t)64 * K + k0);
        uint4 b0 = *(const uint4*)(Bg + k0);
        uint4 b1 = *(const uint4*)(Bg + (size_t)64 * K + k0);
        __syncthreads();
        *(uint4*)&As[r0 * LDT + c0]        = a0;
        *(uint4*)&As[(r0 + 64) * LDT + c0] = a1;
        *(uint4*)&Bs[r0 * LDT + c0]        = b0;
        *(uint4*)&Bs[(r0 + 64) * LDT + c0] = b1;
        __syncthreads();

        v8bf af[4], bfr[4];
#pragma unroll
        for (int mt = 0; mt < 4; mt++)
            af[mt] = *(const v8bf*)&As[(wm + mt * 16 + ln) * LDT + quad * 8];
#pragma unroll
        for (int nt = 0; nt < 4; nt++)
            bfr[nt] = *(const v8bf*)&Bs[(wn + nt * 16 + ln) * LDT + quad * 8];
#pragma unroll
        for (int mt = 0; mt < 4; mt++)
#pragma unroll
            for (int nt = 0; nt < 4; nt++)
                acc[mt][nt] = __builtin_amdgcn_mfma_f32_16x16x32_bf16(af[mt], bfr[nt], acc[mt][nt], 0, 0, 0);
    }

#pragma unroll
    for (int mt = 0; mt < 4; mt++) {
#pragma unroll
        for (int r = 0; r < 4; r++) {
            int row = m0 + wm + mt * 16 + quad * 4 + r;
#pragma unroll
            for (int nt = 0; nt < 4; nt++) {
                int col = n0 + wn + nt * 16 + ln;
                float v = acc[mt][nt][r] + bias[col];
                if (Cf) Cf[(size_t)row * N + col] = v + resid[(size_t)row * N + col];
                else    Cb[(size_t)row * N + col] = (bf16_t)v;
            }
        }
    }
}

// ---------------------------------------------------------------- V transpose: qkv V-cols -> Vt[bh][d][s]
// 64x64 bf16 tile = 4096 elems = 512 8-elem chunks; 256 threads x 2 iters.
__global__ __launch_bounds__(256) void k_transpose_v(const bf16_t* __restrict__ qkv,
                                                     bf16_t* __restrict__ vt) {
    __shared__ bf16_t tile[64 * 72];
    int bid = blockIdx.x;
    int st = bid & 31, bh = bid >> 5, b = bh >> 4, h = bh & 15;
    int t = threadIdx.x;
    const bf16_t* src = qkv + (size_t)(b * SEQ + st * 64) * 3072 + 2048 + h * 64;
#pragma unroll
    for (int i = 0; i < 2; i++) {
        int c = t + i * 256, row = c >> 3, c8 = (c & 7) << 3;   // row in [0,64)
        *(uint4*)&tile[row * 72 + c8] = *(const uint4*)(src + (size_t)row * 3072 + c8);
    }
    __syncthreads();
    bf16_t* dst = vt + (size_t)bh * DHEAD * SEQ + st * 64;
#pragma unroll
    for (int i = 0; i < 2; i++) {
        int c = t + i * 256, d = c >> 3, s8 = (c & 7) << 3;     // d in [0,64)
        v8bf o;
#pragma unroll
        for (int j = 0; j < 8; j++) o[j] = tile[(s8 + j) * 72 + d];
        *(v8bf*)(dst + (size_t)d * SEQ + s8) = o;
    }
}

// ---------------------------------------------------------------- flash attention
// grid: B*H*(S/64) blocks, 256 thr (4 waves x 16 q-rows). K read direct from global,
// V from Vt (pre-transposed), P via per-wave LDS round-trip (C-layout -> A-layout).
__global__ __launch_bounds__(256, 2) void k_attn(const bf16_t* __restrict__ qkv,
                                                 const bf16_t* __restrict__ vt,
                                                 bf16_t* __restrict__ attn) {
    __shared__ bf16_t Pl[4][16 * 72];
    const float SC = 0.125f * 1.44269504088896f;  // 1/sqrt(64) * log2(e)
    int bid = blockIdx.x;
    int qt = bid & 31, bh = bid >> 5, b = bh >> 4, h = bh & 15;
    int t = threadIdx.x, w = t >> 6, lane = t & 63, quad = lane >> 4, ln = lane & 15;
    int q0 = qt * 64 + w * 16;

    const bf16_t* Qp = qkv + (size_t)(b * SEQ + q0 + ln) * 3072 + h * 64 + quad * 8;
    v8bf qf0 = *(const v8bf*)Qp;
    v8bf qf1 = *(const v8bf*)(Qp + 32);

    const bf16_t* Kb = qkv + (size_t)(b * SEQ) * 3072 + 1024 + h * 64 + quad * 8;
    const bf16_t* Vb = vt + (size_t)bh * DHEAD * SEQ;
    bf16_t* Pw = &Pl[w][0];

    v4f o[4];
#pragma unroll
    for (int d = 0; d < 4; d++) o[d] = (v4f){0.f, 0.f, 0.f, 0.f};
    float mrow[4] = {-1e30f, -1e30f, -1e30f, -1e30f};
    float lrow[4] = {0.f, 0.f, 0.f, 0.f};

    for (int kt = 0; kt < SEQ; kt += 64) {
        v4f s[4];
#pragma unroll
        for (int nt = 0; nt < 4; nt++) s[nt] = (v4f){0.f, 0.f, 0.f, 0.f};
#pragma unroll
        for (int nt = 0; nt < 4; nt++) {
            const bf16_t* kp = Kb + (size_t)(kt + nt * 16 + ln) * 3072;
            s[nt] = __builtin_amdgcn_mfma_f32_16x16x32_bf16(qf0, *(const v8bf*)kp, s[nt], 0, 0, 0);
            s[nt] = __builtin_amdgcn_mfma_f32_16x16x32_bf16(qf1, *(const v8bf*)(kp + 32), s[nt], 0, 0, 0);
        }
        float alpha[4];
#pragma unroll
        for (int r = 0; r < 4; r++) {
            float mx = fmaxf(fmaxf(s[0][r], s[1][r]), fmaxf(s[2][r], s[3][r])) * SC;
#pragma unroll
            for (int off = 1; off < 16; off <<= 1) mx = fmaxf(mx, __shfl_xor(mx, off));
            float mnew = fmaxf(mrow[r], mx);
            alpha[r] = exp2f(mrow[r] - mnew);
            float rs = 0.f;
#pragma unroll
            for (int nt = 0; nt < 4; nt++) {
                float p = exp2f(s[nt][r] * SC - mnew);
                Pw[(quad * 4 + r) * 72 + nt * 16 + ln] = (bf16_t)p;
                rs += p;
            }
#pragma unroll
            for (int off = 1; off < 16; off <<= 1) rs += __shfl_xor(rs, off);
            lrow[r] = lrow[r] * alpha[r] + rs;
            mrow[r] = mnew;
        }
#pragma unroll
        for (int d = 0; d < 4; d++) {
            o[d][0] *= alpha[0]; o[d][1] *= alpha[1];
            o[d][2] *= alpha[2]; o[d][3] *= alpha[3];
        }
        // P (A-layout) x Vt
#pragma unroll
        for (int tk = 0; tk < 2; tk++) {
            v8bf pf = *(const v8bf*)&Pw[ln * 72 + tk * 32 + quad * 8];
#pragma unroll
            for (int d = 0; d < 4; d++) {
                v8bf vf = *(const v8bf*)(Vb + (size_t)(d * 16 + ln) * SEQ + kt + tk * 32 + quad * 8);
                o[d] = __builtin_amdgcn_mfma_f32_16x16x32_bf16(pf, vf, o[d], 0, 0, 0);
            }
        }
    }
    int rowg = b * SEQ + q0;
#pragma unroll
    for (int r = 0; r < 4; r++) {
        float inv = 1.f / lrow[r];
#pragma unroll
        for (int d = 0; d < 4; d++)
            attn[(size_t)(rowg + quad * 4 + r) * D_MODEL + h * 64 + d * 16 + ln] =
                (bf16_t)(o[d][r] * inv);
    }
}

// ---------------------------------------------------------------- LayerNorm (one row / block)
__global__ __launch_bounds__(256) void k_layernorm(const float* __restrict__ y,
                                                   const float* __restrict__ g,
                                                   const float* __restrict__ beta,
                                                   float* __restrict__ out) {
    __shared__ float rs[4], rq[4];
    int row = blockIdx.x, t = threadIdx.x;
    int w = t >> 6, lane = t & 63;
    float4 v = ((const float4*)(y + (size_t)row * D_MODEL))[t];
    float s = v.x + v.y + v.z + v.w;
    float q = v.x * v.x + v.y * v.y + v.z * v.z + v.w * v.w;
#pragma unroll
    for (int off = 1; off < 64; off <<= 1) {
        s += __shfl_xor(s, off);
        q += __shfl_xor(q, off);
    }
    if (lane == 0) { rs[w] = s; rq[w] = q; }
    __syncthreads();
    s = rs[0] + rs[1] + rs[2] + rs[3];
    q = rq[0] + rq[1] + rq[2] + rq[3];
    float mu = s * (1.f / D_MODEL);
    float var = q * (1.f / D_MODEL) - mu * mu;
    float rstd = rsqrtf(var + 1e-5f);
    float4 gg = ((const float4*)g)[t];
    float4 bb = ((const float4*)beta)[t];
    float4 o;
    o.x = (v.x - mu) * rstd * gg.x + bb.x;
    o.y = (v.y - mu) * rstd * gg.y + bb.y;
    o.z = (v.z - mu) * rstd * gg.z + bb.z;
    o.w = (v.w - mu) * rstd * gg.w + bb.w;
    ((float4*)(out + (size_t)row * D_MODEL))[t] = o;
}

// ---------------------------------------------------------------- launch
extern "C" void kernel_launch(void* const* d_in, const int* in_sizes, int n_in,
                              void* d_out, int out_size, void* d_ws, size_t ws_size,
                              hipStream_t stream) {
    const float* batch = (const float*)d_in[0];
    const float* wq = (const float*)d_in[1];
    const float* bq = (const float*)d_in[2];
    const float* wk = (const float*)d_in[3];
    const float* bk = (const float*)d_in[4];
    const float* wv = (const float*)d_in[5];
    const float* bv = (const float*)d_in[6];
    const float* wo = (const float*)d_in[7];
    const float* bo = (const float*)d_in[8];
    const float* ln_g = (const float*)d_in[9];
    const float* ln_b = (const float*)d_in[10];
    float* out = (float*)d_out;

    char* ws = (char*)d_ws;
    // workspace layout (all offsets 256B aligned)
    size_t offXb   = 0;                               // 16,777,216  bf16 X  (later reused as Vt)
    size_t offWqkv = offXb + (size_t)ROWS * D_MODEL * 2;        // + 6,291,456
    size_t offWo   = offWqkv + (size_t)3072 * 1024 * 2;         // + 2,097,152
    size_t offBias = offWo + (size_t)1024 * 1024 * 2;           // + 12,288
    size_t offQKV  = offBias + 3072 * 4;                        // + 50,331,648 (bf16 qkv; later fp32 y)
    size_t offAttn = offQKV + (size_t)ROWS * 3072 * 2;          // + 16,777,216
    size_t total   = offAttn + (size_t)ROWS * D_MODEL * 2;      // = 92,286,976
    if (ws_size < total) return;  // workspace too small -> fail loudly via validation

    bf16_t* Xb   = (bf16_t*)(ws + offXb);
    bf16_t* Vt   = (bf16_t*)(ws + offXb);    // alias: X dead after GEMM1
    bf16_t* Wqkv = (bf16_t*)(ws + offWqkv);
    bf16_t* Wob  = (bf16_t*)(ws + offWo);
    float*  bqkv = (float*)(ws + offBias);
    bf16_t* qkv  = (bf16_t*)(ws + offQKV);
    float*  y    = (float*)(ws + offQKV);    // alias: qkv dead after attention
    bf16_t* attn = (bf16_t*)(ws + offAttn);

    // prep: casts + weight/bias packing
    k_f32_to_bf16<<<8192, 256, 0, stream>>>(batch, Xb, 2097152);
    k_f32_to_bf16<<<1024, 256, 0, stream>>>(wq, Wqkv, 262144);
    k_f32_to_bf16<<<1024, 256, 0, stream>>>(wk, Wqkv + 1048576, 262144);
    k_f32_to_bf16<<<1024, 256, 0, stream>>>(wv, Wqkv + 2097152, 262144);
    k_f32_to_bf16<<<1024, 256, 0, stream>>>(wo, Wob, 262144);
    k_pack_bias<<<4, 256, 0, stream>>>(bq, bk, bv, bqkv);

    // QKV projection: [8192,1024] x [3072,1024]^T -> qkv [8192,3072] bf16
    k_gemm_bt<<<64 * 24, 256, 0, stream>>>(Xb, Wqkv, bqkv, nullptr, qkv, nullptr,
                                           8192, 3072, 1024);
    // V transpose for PV-friendly layout
    k_transpose_v<<<2048, 256, 0, stream>>>(qkv, Vt);
    // flash attention -> attn [8192,1024] bf16
    k_attn<<<2048, 256, 0, stream>>>(qkv, Vt, attn);
    // output projection + bias + residual -> y fp32
    k_gemm_bt<<<64 * 8, 256, 0, stream>>>(attn, Wob, bo, batch, nullptr, y,
                                          8192, 1024, 1024);
    // layernorm -> out
    k_layernorm<<<8192, 256, 0, stream>>>(y, ln_g, ln_b, out);
}